// Round 12
// baseline (164.260 us; speedup 1.0000x reference)
//
#include <hip/hip_runtime.h>
#include <cmath>

typedef unsigned int uint;
typedef unsigned long long ull;

#define BATCH 32
#define NA 8400
#define NC 80
#define MAXDET 100
#define NMSTHR 0.65f
#define SCTHR 0.01f

#define NT 512          // NMS threads per block (8 waves: halves barrier spread)
#define NW (NT / 64)
#define EPT 17          // ceil(NA / NT)
#define NBINS 4096      // histogram bins on key[31:20]
#define CAP 512         // candidate buffer (giant-bin overflow safety)
#define WTGT 256u       // window target size

#define DGROUPS 132     // 64-anchor groups per image: 100 (L0) + 25 (L1) + 7 (L2)

__device__ __forceinline__ float stable_sigmoid(float x) {
    if (x >= 0.f) return 1.f / (1.f + expf(-x));
    float e = expf(x);
    return e / (1.f + e);
}

// ---------------- decode: one 256-thread block per 64 anchors (r7-EXACT) ----
// Wave w scans channels [20w, 20w+20) for the block's 64 consecutive anchors:
// every load is uniform-base + lane*4 -> ONE 256B contiguous segment per wave
// instruction. Per-wave (max, argmax) in registers with strict '>' (first
// max); 2KB LDS merge in ascending wave order -> exact jnp.argmax semantics.
// Wave 0 runs the reg/obj/box epilogue with unit-stride loads/stores.
// No atomics, no function tails (r4 regalloc lesson), no store->reload (r3).
template<int HW, int W, int S>
__device__ __forceinline__ void decode_blk(
    const float* __restrict__ cls, const float* __restrict__ reg,
    const float* __restrict__ obj, int b, int p0, int w, int lane, int ag0,
    float (*s_m)[64], int (*s_c)[64],
    float4* __restrict__ wboxes, int* __restrict__ wlabels, uint* __restrict__ wkeys)
{
    int p = p0 + lane;
    bool valid = (p < HW);            // only the last L2 group has invalid lanes
    int pc = valid ? p : (HW - 1);    // clamped for safe (dup) loads

    const float* cbase = cls + (size_t)b * NC * HW + (size_t)(w * 20) * HW + pc;
    float v[20];
    #pragma unroll
    for (int i = 0; i < 20; ++i) v[i] = cbase[(size_t)i * HW];
    float m = v[0]; int c = 0;
    #pragma unroll
    for (int i = 1; i < 20; ++i)
        if (v[i] > m) { m = v[i]; c = i; }     // strict > -> first max in slice

    s_m[w][lane] = m;
    s_c[w][lane] = c + w * 20;
    __syncthreads();

    if (w == 0) {
        float mm = s_m[0][lane]; int cc = s_c[0][lane];
        #pragma unroll
        for (int ww = 1; ww < 4; ++ww) {
            float om = s_m[ww][lane]; int oc = s_c[ww][lane];
            if (om > mm) { mm = om; cc = oc; } // strict > keeps lowest channel
        }
        const float* rb = reg + (size_t)b * 4 * HW + pc;
        float r0 = rb[0];
        float r1 = rb[HW];
        float r2 = rb[2 * (size_t)HW];
        float r3 = rb[3 * (size_t)HW];
        float ov = obj[(size_t)b * HW + pc];

        int y = pc / W;               // W constexpr -> magic mul
        int x = pc - y * W;
        float sc = stable_sigmoid(mm) * stable_sigmoid(ov);
        float cx = r0 * (float)S + (float)x * (float)S;
        float cy = r1 * (float)S + (float)y * (float)S;
        float bw = expf(r2) * (float)S;
        float bh = expf(r3) * (float)S;

        if (valid) {
            int ag = ag0 + lane;
            wboxes[ag]  = make_float4(cx - bw * 0.5f, cy - bh * 0.5f,
                                      cx + bw * 0.5f, cy + bh * 0.5f);
            wlabels[ag] = cc;
            wkeys[ag]   = (sc >= SCTHR) ? ~__float_as_uint(sc) : 0xFFFFFFFFu;
        }
    }
}

__global__ __launch_bounds__(256) void decode_kernel(
    const float* __restrict__ cls0, const float* __restrict__ reg0, const float* __restrict__ obj0,
    const float* __restrict__ cls1, const float* __restrict__ reg1, const float* __restrict__ obj1,
    const float* __restrict__ cls2, const float* __restrict__ reg2, const float* __restrict__ obj2,
    float4* __restrict__ wboxes, int* __restrict__ wlabels, uint* __restrict__ wkeys)
{
    __shared__ float s_m[4][64];
    __shared__ int   s_c[4][64];

    int bid  = blockIdx.x;            // BATCH * DGROUPS blocks
    int b    = bid / DGROUPS;         // literal divisor -> magic mul
    int g    = bid - b * DGROUPS;
    int t    = threadIdx.x;
    int w    = t >> 6;
    int lane = t & 63;

    if (g < 100) {
        int p0 = g * 64;
        decode_blk<6400, 80, 8>(cls0, reg0, obj0, b, p0, w, lane,
                                b * NA + p0, s_m, s_c, wboxes, wlabels, wkeys);
    } else if (g < 125) {
        int p0 = (g - 100) * 64;
        decode_blk<1600, 40, 16>(cls1, reg1, obj1, b, p0, w, lane,
                                 b * NA + 6400 + p0, s_m, s_c, wboxes, wlabels, wkeys);
    } else {
        int p0 = (g - 125) * 64;
        decode_blk<400, 20, 32>(cls2, reg2, obj2, b, p0, w, lane,
                                b * NA + 8000 + p0, s_m, s_c, wboxes, wlabels, wkeys);
    }
}

// ---------------- NMS via sorted walk (r11 + NT=512 + fused scatter/prefetch)
// vs r11 (43.0 us), two serial-chain cuts:
// (1) NT 1024->512: 8-wave barriers instead of 16 across the ~13 block-wide
//     barriers (arrival spread halves). Sweep EPT 9->17 (same bytes, still
//     pipelined); scan 8 bins/thread.
// (2) scatter+prefetch fused: after the rank loop each thread holds
//     (rank, key) in registers, so it scatters s_skey[rank] AND prefetches
//     boxes/labels into s_cbox[rank]/s_ca/s_clb in the SAME phase -- one
//     fewer barrier + one fewer LDS read round, global loads issued earlier.
__global__ __launch_bounds__(NT) void nms_kernel(
    const float4* __restrict__ wboxes, const int* __restrict__ wlabels,
    const uint* __restrict__ wkeys, float* __restrict__ out)
{
    int b = blockIdx.x;
    int t = threadIdx.x;
    int lane = t & 63;
    int wv = t >> 6;
    const float4* boxes  = wboxes  + (size_t)b * NA;
    const int*    labels = wlabels + (size_t)b * NA;
    const uint*   keys   = wkeys   + (size_t)b * NA;

    __shared__ uint   s_hist[NBINS];
    __shared__ uint   s_cum[NBINS + 1];    // exclusive prefix
    __shared__ uint   s_wsum[NW];
    __shared__ ull    s_skey[CAP];
    __shared__ float4 s_cbox[CAP];         // candidate OFFSET boxes (prefetched)
    __shared__ float  s_ca[CAP];           // candidate offset-box areas
    __shared__ int    s_clb[CAP];          // candidate labels
    __shared__ float  s_kbox[MAXDET][4];   // kept OFFSET boxes
    __shared__ float  s_ka1[MAXDET];
    __shared__ int    s_kidx[MAXDET];
    __shared__ float  s_kscr[MAXDET];
    __shared__ int    s_klab[MAXDET];
    __shared__ float  s_red[NW];
    __shared__ float  s_off;
    __shared__ int    s_kept, s_winlo, s_winhi, s_nsel;

    // ---- zero hist; FUSED sweep: max|coord| + key histogram + key cache ----
    for (int i = t; i < NBINS; i += NT) s_hist[i] = 0;
    if (t == 0) { s_kept = 0; s_winlo = 0; }
    __syncthreads();
    float m = 0.f;
    uint kreg[EPT];                        // per-thread key cache (const-indexed)
    #pragma unroll
    for (int w = 0; w < EPT; ++w) {
        int e = t + w * NT;
        kreg[w] = 0xFFFFFFFFu;
        if (e < NA) {
            float4 v = boxes[e];
            m = fmaxf(m, fmaxf(fmaxf(fabsf(v.x), fabsf(v.y)),
                               fmaxf(fabsf(v.z), fabsf(v.w))));
            uint k = keys[e];
            kreg[w] = k;
            if (k != 0xFFFFFFFFu) atomicAdd(&s_hist[k >> 20], 1u);
        }
    }
    #pragma unroll
    for (int o = 32; o >= 1; o >>= 1) m = fmaxf(m, __shfl_xor(m, o));
    if (lane == 0) s_red[wv] = m;
    __syncthreads();
    if (t == 0) {
        float mm = 0.f;
        for (int w = 0; w < NW; ++w) mm = fmaxf(mm, s_red[w]);
        s_off = mm + 1.f;
    }

    // ---- exclusive scan over 4096 bins: 8 bins/thread + shfl scans ----
    uint l[8];
    uint L = 0;
    #pragma unroll
    for (int i = 0; i < 8; ++i) { l[i] = s_hist[8 * t + i]; L += l[i]; }
    uint ls = L;
    #pragma unroll
    for (int o = 1; o < 64; o <<= 1) {
        uint v = __shfl_up(ls, o);
        if (lane >= o) ls += v;
    }
    if (lane == 63) s_wsum[wv] = ls;
    __syncthreads();
    if (t < NW) {
        uint v = s_wsum[t];
        uint vs = v;
        #pragma unroll
        for (int o = 1; o < NW; o <<= 1) {
            uint u = __shfl_up(vs, o);
            if (t >= o) vs += u;
        }
        s_wsum[t] = vs - v;
    }
    __syncthreads();
    {
        uint run = s_wsum[wv] + (ls - L);
        #pragma unroll
        for (int i = 0; i < 8; ++i) { s_cum[8 * t + i] = run; run += l[i]; }
        if (t == NT - 1) s_cum[NBINS] = run;
    }
    float off;

    // ---- window loop (typically runs once) ----
    for (;;) {
        __syncthreads();
        int kept = s_kept, winlo = s_winlo;
        uint remaining = s_cum[NBINS] - s_cum[winlo];
        if (kept >= MAXDET || winlo >= NBINS || remaining == 0u) break;
        if (t == 0) { s_winhi = winlo + 1; s_nsel = 0; }   // giant-bin clamp floor
        s_skey[t] = ~0ull;                                  // NT == CAP
        __syncthreads();
        // winhi via unique-boundary store: pred(i) = cum[i+1]-cl <= WTGT is
        // monotone non-increasing in i, so exactly one i has pred(i) && !pred(i+1).
        uint cl = s_cum[winlo];
        #pragma unroll
        for (int q = 0; q < 8; ++q) {
            int i = t + q * NT;
            if (i >= winlo && i < NBINS) {
                bool p0 = (s_cum[i + 1] - cl) <= WTGT;
                bool p1 = (i + 1 < NBINS) && ((s_cum[i + 2] - cl) <= WTGT);
                if (p0 && !p1) s_winhi = i + 1;   // unique writer
            }
        }
        __syncthreads();
        int winhi = s_winhi;

        // wave-aggregated compaction of window candidates (keys from REGISTERS)
        #pragma unroll
        for (int w = 0; w < EPT; ++w) {
            int e = t + w * NT;
            uint k = kreg[w];
            bool q = false;
            if (k != 0xFFFFFFFFu) {
                int bin = (int)(k >> 20);
                q = (bin >= winlo && bin < winhi);
            }
            ull mask = __ballot(q);
            if (mask) {
                int leader = __ffsll(mask) - 1;
                int pbase = 0;
                if (lane == leader) pbase = atomicAdd(&s_nsel, __popcll(mask));
                pbase = __shfl(pbase, leader);
                if (q) {
                    int pos = pbase + __popcll(mask & ((1ull << lane) - 1ull));
                    if (pos < CAP) s_skey[pos] = ((ull)k << 32) | (uint)e;
                }
            }
        }
        __syncthreads();
        int nsel = s_nsel; if (nsel > CAP) nsel = CAP;

        // O(n) rank-placement sort: position = count of smaller keys (keys
        // totally ordered via embedded anchor idx). Uniform LDS broadcast
        // loop; then scatter s_skey[rank] AND prefetch the candidate's
        // box/label into s_cbox[rank]/s_ca/s_clb in the SAME phase (the
        // thread holds rank+key in registers -- no re-read of sorted keys).
        off = s_off;
        ull myk = (t < nsel) ? s_skey[t] : ~0ull;
        int rank = 0;
        if (t < nsel) {
            for (int j = 0; j < nsel; ++j)
                rank += (s_skey[j] < myk) ? 1 : 0;
        }
        __syncthreads();
        if (t < nsel) {
            s_skey[rank] = myk;
            int idx = (int)(myk & 0xFFFFFFFFull);
            float4 rb = boxes[idx];
            int lb = labels[idx];
            float lo = (float)lb * off;
            float c0 = rb.x + lo, c1 = rb.y + lo;
            float c2 = rb.z + lo, c3 = rb.w + lo;
            s_cbox[rank] = make_float4(c0, c1, c2, c3);
            s_ca[rank]   = (c2 - c0) * (c3 - c1);
            s_clb[rank]  = lb;
        }
        __syncthreads();

        // sorted walk on wave 0 (per-accept IoU; 5 shfls + lane-f writes)
        if (t < 64) {
            int kept2 = s_kept;
            for (int cb = 0; cb < nsel && kept2 < MAXDET; cb += 64) {
                int ci = cb + lane;
                ull sk = (ci < nsel) ? s_skey[ci] : ~0ull;
                bool has = (sk != ~0ull);
                int idx = 0, lab = 0;
                float sc = 0.f, c0 = 0.f, c1 = 0.f, c2 = 0.f, c3 = 0.f, ca = 0.f;
                if (has) {
                    idx = (int)(sk & 0xFFFFFFFFull);
                    sc  = __uint_as_float(~(uint)(sk >> 32));   // exact score bits
                    float4 cbx = s_cbox[ci];
                    c0 = cbx.x; c1 = cbx.y; c2 = cbx.z; c3 = cbx.w;
                    ca = s_ca[ci];
                    lab = s_clb[ci];
                    for (int q = 0; q < kept2; ++q) {
                        float tlx = fmaxf(s_kbox[q][0], c0);
                        float tly = fmaxf(s_kbox[q][1], c1);
                        float brx = fminf(s_kbox[q][2], c2);
                        float bry = fminf(s_kbox[q][3], c3);
                        float ww = fmaxf(brx - tlx, 0.f);
                        float hh = fmaxf(bry - tly, 0.f);
                        float inter = ww * hh;
                        float iou = inter / (s_ka1[q] + ca - inter + 1e-6f);
                        if (iou > NMSTHR) { has = false; break; }
                    }
                }
                ull am = __ballot(has);
                while (am && kept2 < MAXDET) {
                    int f = __ffsll(am) - 1;
                    float f0 = __shfl(c0, f), f1 = __shfl(c1, f);
                    float f2 = __shfl(c2, f), f3 = __shfl(c3, f);
                    float fa = __shfl(ca, f);
                    if (lane == f) {
                        s_kbox[kept2][0] = c0; s_kbox[kept2][1] = c1;
                        s_kbox[kept2][2] = c2; s_kbox[kept2][3] = c3;
                        s_ka1[kept2] = ca; s_kidx[kept2] = idx;
                        s_kscr[kept2] = sc; s_klab[kept2] = lab;
                        has = false;
                    }
                    kept2++;
                    if (has) {
                        float tlx = fmaxf(f0, c0), tly = fmaxf(f1, c1);
                        float brx = fminf(f2, c2), bry = fminf(f3, c3);
                        float ww = fmaxf(brx - tlx, 0.f), hh = fmaxf(bry - tly, 0.f);
                        float inter = ww * hh;
                        float iou = inter / (fa + ca - inter + 1e-6f);
                        if (iou > NMSTHR) has = false;
                    }
                    am = __ballot(has);
                }
            }
            if (lane == 0) s_kept = kept2;
        }
        __syncthreads();
        if (t == 0) s_winlo = s_winhi;
    }
    __syncthreads();

    // ---- epilogue: boxes/scores/labels/valid (fp32) ----
    if (t < MAXDET) {
        int kept = s_kept;
        float4 obx = make_float4(0.f, 0.f, 0.f, 0.f);
        float osc = 0.f, olab = -1.f, oval = 0.f;
        if (t < kept) {
            int idx = s_kidx[t];
            obx  = boxes[idx];              // raw (non-offset) box
            osc  = s_kscr[t];
            olab = (float)s_klab[t];
            oval = 1.f;
        }
        float* ob = out + ((size_t)b * MAXDET + t) * 4;
        ob[0] = obx.x; ob[1] = obx.y; ob[2] = obx.z; ob[3] = obx.w;
        out[BATCH * MAXDET * 4 + b * MAXDET + t] = osc;
        out[BATCH * MAXDET * 5 + b * MAXDET + t] = olab;
        out[BATCH * MAXDET * 6 + b * MAXDET + t] = oval;
    }
}

extern "C" void kernel_launch(void* const* d_in, const int* in_sizes, int n_in,
                              void* d_out, int out_size, void* d_ws, size_t ws_size,
                              hipStream_t stream) {
    // setup_inputs() dict order: cls0, reg0, obj0, cls1, reg1, obj1, cls2, reg2, obj2
    const float* cls0 = (const float*)d_in[0];
    const float* reg0 = (const float*)d_in[1];
    const float* obj0 = (const float*)d_in[2];
    const float* cls1 = (const float*)d_in[3];
    const float* reg1 = (const float*)d_in[4];
    const float* obj1 = (const float*)d_in[5];
    const float* cls2 = (const float*)d_in[6];
    const float* reg2 = (const float*)d_in[7];
    const float* obj2 = (const float*)d_in[8];

    // ws layout: boxes | labels | keys
    char* ws = (char*)d_ws;
    size_t nBA = (size_t)BATCH * NA;
    float4* wboxes  = (float4*)ws;
    int*    wlabels = (int*)(ws + nBA * 16);
    uint*   wkeys   = (uint*)(ws + nBA * 20);

    decode_kernel<<<BATCH * DGROUPS, 256, 0, stream>>>(
        cls0, reg0, obj0, cls1, reg1, obj1, cls2, reg2, obj2,
        wboxes, wlabels, wkeys);

    nms_kernel<<<BATCH, NT, 0, stream>>>(wboxes, wlabels, wkeys, (float*)d_out);
}

// Round 13
// 160.763 us; speedup vs baseline: 1.0217x; 1.0217x over previous
//
#include <hip/hip_runtime.h>
#include <cmath>

typedef unsigned int uint;
typedef unsigned long long ull;

#define BATCH 32
#define NA 8400
#define NC 80
#define MAXDET 100
#define NMSTHR 0.65f
#define SCTHR 0.01f

#define NT 1024         // NMS threads per block (16 waves -- r12 proved 8 is worse:
                        // front-half sweeps are TLP-limited, not barrier-bound)
#define NW (NT / 64)
#define EPT 9           // ceil(NA / NT)
#define NBINS 4096      // histogram bins on key[31:20]
#define CAP 512         // candidate buffer (giant-bin overflow safety)
#define WTGT 256u       // window target size

#define DGROUPS 132     // 64-anchor groups per image: 100 (L0) + 25 (L1) + 7 (L2)

__device__ __forceinline__ float stable_sigmoid(float x) {
    if (x >= 0.f) return 1.f / (1.f + expf(-x));
    float e = expf(x);
    return e / (1.f + e);
}

// ---------------- decode: one 256-thread block per 64 anchors (r7-EXACT) ----
// Wave w scans channels [20w, 20w+20) for the block's 64 consecutive anchors:
// every load is uniform-base + lane*4 -> ONE 256B contiguous segment per wave
// instruction. Per-wave (max, argmax) in registers with strict '>' (first
// max); 2KB LDS merge in ascending wave order -> exact jnp.argmax semantics.
// Wave 0 runs the reg/obj/box epilogue with unit-stride loads/stores.
// No atomics, no function tails (r4 regalloc lesson), no store->reload (r3).
template<int HW, int W, int S>
__device__ __forceinline__ void decode_blk(
    const float* __restrict__ cls, const float* __restrict__ reg,
    const float* __restrict__ obj, int b, int p0, int w, int lane, int ag0,
    float (*s_m)[64], int (*s_c)[64],
    float4* __restrict__ wboxes, int* __restrict__ wlabels, uint* __restrict__ wkeys)
{
    int p = p0 + lane;
    bool valid = (p < HW);            // only the last L2 group has invalid lanes
    int pc = valid ? p : (HW - 1);    // clamped for safe (dup) loads

    const float* cbase = cls + (size_t)b * NC * HW + (size_t)(w * 20) * HW + pc;
    float v[20];
    #pragma unroll
    for (int i = 0; i < 20; ++i) v[i] = cbase[(size_t)i * HW];
    float m = v[0]; int c = 0;
    #pragma unroll
    for (int i = 1; i < 20; ++i)
        if (v[i] > m) { m = v[i]; c = i; }     // strict > -> first max in slice

    s_m[w][lane] = m;
    s_c[w][lane] = c + w * 20;
    __syncthreads();

    if (w == 0) {
        float mm = s_m[0][lane]; int cc = s_c[0][lane];
        #pragma unroll
        for (int ww = 1; ww < 4; ++ww) {
            float om = s_m[ww][lane]; int oc = s_c[ww][lane];
            if (om > mm) { mm = om; cc = oc; } // strict > keeps lowest channel
        }
        const float* rb = reg + (size_t)b * 4 * HW + pc;
        float r0 = rb[0];
        float r1 = rb[HW];
        float r2 = rb[2 * (size_t)HW];
        float r3 = rb[3 * (size_t)HW];
        float ov = obj[(size_t)b * HW + pc];

        int y = pc / W;               // W constexpr -> magic mul
        int x = pc - y * W;
        float sc = stable_sigmoid(mm) * stable_sigmoid(ov);
        float cx = r0 * (float)S + (float)x * (float)S;
        float cy = r1 * (float)S + (float)y * (float)S;
        float bw = expf(r2) * (float)S;
        float bh = expf(r3) * (float)S;

        if (valid) {
            int ag = ag0 + lane;
            wboxes[ag]  = make_float4(cx - bw * 0.5f, cy - bh * 0.5f,
                                      cx + bw * 0.5f, cy + bh * 0.5f);
            wlabels[ag] = cc;
            wkeys[ag]   = (sc >= SCTHR) ? ~__float_as_uint(sc) : 0xFFFFFFFFu;
        }
    }
}

__global__ __launch_bounds__(256) void decode_kernel(
    const float* __restrict__ cls0, const float* __restrict__ reg0, const float* __restrict__ obj0,
    const float* __restrict__ cls1, const float* __restrict__ reg1, const float* __restrict__ obj1,
    const float* __restrict__ cls2, const float* __restrict__ reg2, const float* __restrict__ obj2,
    float4* __restrict__ wboxes, int* __restrict__ wlabels, uint* __restrict__ wkeys)
{
    __shared__ float s_m[4][64];
    __shared__ int   s_c[4][64];

    int bid  = blockIdx.x;            // BATCH * DGROUPS blocks
    int b    = bid / DGROUPS;         // literal divisor -> magic mul
    int g    = bid - b * DGROUPS;
    int t    = threadIdx.x;
    int w    = t >> 6;
    int lane = t & 63;

    if (g < 100) {
        int p0 = g * 64;
        decode_blk<6400, 80, 8>(cls0, reg0, obj0, b, p0, w, lane,
                                b * NA + p0, s_m, s_c, wboxes, wlabels, wkeys);
    } else if (g < 125) {
        int p0 = (g - 100) * 64;
        decode_blk<1600, 40, 16>(cls1, reg1, obj1, b, p0, w, lane,
                                 b * NA + 6400 + p0, s_m, s_c, wboxes, wlabels, wkeys);
    } else {
        int p0 = (g - 125) * 64;
        decode_blk<400, 20, 32>(cls2, reg2, obj2, b, p0, w, lane,
                                b * NA + 8000 + p0, s_m, s_c, wboxes, wlabels, wkeys);
    }
}

// ---------------- NMS via sorted walk (r11 + fused scatter/prefetch ONLY) ---
// Bisect of r12: NT stays 1024 (r12 proved NT=512 regresses -- the sweeps
// are TLP-limited), keeping only the fused scatter+prefetch: after the rank
// loop each thread holds (rank, key) in registers, so it scatters
// s_skey[rank] AND prefetches boxes/labels into s_cbox[rank]/s_ca/s_clb in
// the SAME phase -- one fewer barrier + one fewer LDS read round, and the
// scattered global loads issue one phase earlier.
__global__ __launch_bounds__(NT) void nms_kernel(
    const float4* __restrict__ wboxes, const int* __restrict__ wlabels,
    const uint* __restrict__ wkeys, float* __restrict__ out)
{
    int b = blockIdx.x;
    int t = threadIdx.x;
    int lane = t & 63;
    int wv = t >> 6;
    const float4* boxes  = wboxes  + (size_t)b * NA;
    const int*    labels = wlabels + (size_t)b * NA;
    const uint*   keys   = wkeys   + (size_t)b * NA;

    __shared__ uint   s_hist[NBINS];
    __shared__ uint   s_cum[NBINS + 1];    // exclusive prefix
    __shared__ uint   s_wsum[NW];
    __shared__ ull    s_skey[CAP];
    __shared__ float4 s_cbox[CAP];         // candidate OFFSET boxes (prefetched)
    __shared__ float  s_ca[CAP];           // candidate offset-box areas
    __shared__ int    s_clb[CAP];          // candidate labels
    __shared__ float  s_kbox[MAXDET][4];   // kept OFFSET boxes
    __shared__ float  s_ka1[MAXDET];
    __shared__ int    s_kidx[MAXDET];
    __shared__ float  s_kscr[MAXDET];
    __shared__ int    s_klab[MAXDET];
    __shared__ float  s_red[NW];
    __shared__ float  s_off;
    __shared__ int    s_kept, s_winlo, s_winhi, s_nsel;

    // ---- zero hist; FUSED sweep: max|coord| + key histogram + key cache ----
    for (int i = t; i < NBINS; i += NT) s_hist[i] = 0;
    if (t == 0) { s_kept = 0; s_winlo = 0; }
    __syncthreads();
    float m = 0.f;
    uint kreg[EPT];                        // per-thread key cache (const-indexed)
    #pragma unroll
    for (int w = 0; w < EPT; ++w) {
        int e = t + w * NT;
        kreg[w] = 0xFFFFFFFFu;
        if (e < NA) {
            float4 v = boxes[e];
            m = fmaxf(m, fmaxf(fmaxf(fabsf(v.x), fabsf(v.y)),
                               fmaxf(fabsf(v.z), fabsf(v.w))));
            uint k = keys[e];
            kreg[w] = k;
            if (k != 0xFFFFFFFFu) atomicAdd(&s_hist[k >> 20], 1u);
        }
    }
    #pragma unroll
    for (int o = 32; o >= 1; o >>= 1) m = fmaxf(m, __shfl_xor(m, o));
    if (lane == 0) s_red[wv] = m;
    __syncthreads();
    if (t == 0) {
        float mm = 0.f;
        for (int w = 0; w < NW; ++w) mm = fmaxf(mm, s_red[w]);
        s_off = mm + 1.f;
    }

    // ---- exclusive scan over 4096 bins: 4 bins/thread + shfl scans ----
    uint l0 = s_hist[4 * t], l1 = s_hist[4 * t + 1],
         l2 = s_hist[4 * t + 2], l3 = s_hist[4 * t + 3];
    uint L = l0 + l1 + l2 + l3;
    uint ls = L;
    #pragma unroll
    for (int o = 1; o < 64; o <<= 1) {
        uint v = __shfl_up(ls, o);
        if (lane >= o) ls += v;
    }
    if (lane == 63) s_wsum[wv] = ls;
    __syncthreads();
    if (t < NW) {
        uint v = s_wsum[t];
        uint vs = v;
        #pragma unroll
        for (int o = 1; o < NW; o <<= 1) {
            uint u = __shfl_up(vs, o);
            if ((t & 63) >= o) vs += u;
        }
        s_wsum[t] = vs - v;
    }
    __syncthreads();
    uint base = s_wsum[wv] + (ls - L);
    s_cum[4 * t]     = base;
    s_cum[4 * t + 1] = base + l0;
    s_cum[4 * t + 2] = base + l0 + l1;
    s_cum[4 * t + 3] = base + l0 + l1 + l2;
    if (t == NT - 1) s_cum[NBINS] = base + L;
    float off;

    // ---- window loop (typically runs once) ----
    for (;;) {
        __syncthreads();
        int kept = s_kept, winlo = s_winlo;
        uint remaining = s_cum[NBINS] - s_cum[winlo];
        if (kept >= MAXDET || winlo >= NBINS || remaining == 0u) break;
        if (t == 0) { s_winhi = winlo + 1; s_nsel = 0; }   // giant-bin clamp floor
        if (t < CAP) s_skey[t] = ~0ull;
        __syncthreads();
        // winhi via unique-boundary store: pred(i) = cum[i+1]-cl <= WTGT is
        // monotone non-increasing in i, so exactly one i has pred(i) && !pred(i+1).
        uint cl = s_cum[winlo];
        #pragma unroll
        for (int q = 0; q < 4; ++q) {
            int i = t + q * NT;
            if (i >= winlo && i < NBINS) {
                bool p0 = (s_cum[i + 1] - cl) <= WTGT;
                bool p1 = (i + 1 < NBINS) && ((s_cum[i + 2] - cl) <= WTGT);
                if (p0 && !p1) s_winhi = i + 1;   // unique writer
            }
        }
        __syncthreads();
        int winhi = s_winhi;

        // wave-aggregated compaction of window candidates (keys from REGISTERS)
        #pragma unroll
        for (int w = 0; w < EPT; ++w) {
            int e = t + w * NT;
            uint k = kreg[w];
            bool q = false;
            if (k != 0xFFFFFFFFu) {
                int bin = (int)(k >> 20);
                q = (bin >= winlo && bin < winhi);
            }
            ull mask = __ballot(q);
            if (mask) {
                int leader = __ffsll(mask) - 1;
                int pbase = 0;
                if (lane == leader) pbase = atomicAdd(&s_nsel, __popcll(mask));
                pbase = __shfl(pbase, leader);
                if (q) {
                    int pos = pbase + __popcll(mask & ((1ull << lane) - 1ull));
                    if (pos < CAP) s_skey[pos] = ((ull)k << 32) | (uint)e;
                }
            }
        }
        __syncthreads();
        int nsel = s_nsel; if (nsel > CAP) nsel = CAP;

        // O(n) rank-placement sort: position = count of smaller keys (keys
        // totally ordered via embedded anchor idx). Uniform LDS broadcast
        // loop; then scatter s_skey[rank] AND prefetch the candidate's
        // box/label into s_cbox[rank]/s_ca/s_clb in the SAME phase (the
        // thread holds rank+key in registers -- no re-read of sorted keys).
        off = s_off;
        ull myk = (t < nsel) ? s_skey[t] : ~0ull;
        int rank = 0;
        if (t < nsel) {
            for (int j = 0; j < nsel; ++j)
                rank += (s_skey[j] < myk) ? 1 : 0;
        }
        __syncthreads();
        if (t < nsel) {
            s_skey[rank] = myk;
            int idx = (int)(myk & 0xFFFFFFFFull);
            float4 rb = boxes[idx];
            int lb = labels[idx];
            float lo = (float)lb * off;
            float c0 = rb.x + lo, c1 = rb.y + lo;
            float c2 = rb.z + lo, c3 = rb.w + lo;
            s_cbox[rank] = make_float4(c0, c1, c2, c3);
            s_ca[rank]   = (c2 - c0) * (c3 - c1);
            s_clb[rank]  = lb;
        }
        __syncthreads();

        // sorted walk on wave 0 (per-accept IoU; 5 shfls + lane-f writes)
        if (t < 64) {
            int kept2 = s_kept;
            for (int cb = 0; cb < nsel && kept2 < MAXDET; cb += 64) {
                int ci = cb + lane;
                ull sk = (ci < nsel) ? s_skey[ci] : ~0ull;
                bool has = (sk != ~0ull);
                int idx = 0, lab = 0;
                float sc = 0.f, c0 = 0.f, c1 = 0.f, c2 = 0.f, c3 = 0.f, ca = 0.f;
                if (has) {
                    idx = (int)(sk & 0xFFFFFFFFull);
                    sc  = __uint_as_float(~(uint)(sk >> 32));   // exact score bits
                    float4 cbx = s_cbox[ci];
                    c0 = cbx.x; c1 = cbx.y; c2 = cbx.z; c3 = cbx.w;
                    ca = s_ca[ci];
                    lab = s_clb[ci];
                    for (int q = 0; q < kept2; ++q) {
                        float tlx = fmaxf(s_kbox[q][0], c0);
                        float tly = fmaxf(s_kbox[q][1], c1);
                        float brx = fminf(s_kbox[q][2], c2);
                        float bry = fminf(s_kbox[q][3], c3);
                        float ww = fmaxf(brx - tlx, 0.f);
                        float hh = fmaxf(bry - tly, 0.f);
                        float inter = ww * hh;
                        float iou = inter / (s_ka1[q] + ca - inter + 1e-6f);
                        if (iou > NMSTHR) { has = false; break; }
                    }
                }
                ull am = __ballot(has);
                while (am && kept2 < MAXDET) {
                    int f = __ffsll(am) - 1;
                    float f0 = __shfl(c0, f), f1 = __shfl(c1, f);
                    float f2 = __shfl(c2, f), f3 = __shfl(c3, f);
                    float fa = __shfl(ca, f);
                    if (lane == f) {
                        s_kbox[kept2][0] = c0; s_kbox[kept2][1] = c1;
                        s_kbox[kept2][2] = c2; s_kbox[kept2][3] = c3;
                        s_ka1[kept2] = ca; s_kidx[kept2] = idx;
                        s_kscr[kept2] = sc; s_klab[kept2] = lab;
                        has = false;
                    }
                    kept2++;
                    if (has) {
                        float tlx = fmaxf(f0, c0), tly = fmaxf(f1, c1);
                        float brx = fminf(f2, c2), bry = fminf(f3, c3);
                        float ww = fmaxf(brx - tlx, 0.f), hh = fmaxf(bry - tly, 0.f);
                        float inter = ww * hh;
                        float iou = inter / (fa + ca - inter + 1e-6f);
                        if (iou > NMSTHR) has = false;
                    }
                    am = __ballot(has);
                }
            }
            if (lane == 0) s_kept = kept2;
        }
        __syncthreads();
        if (t == 0) s_winlo = s_winhi;
    }
    __syncthreads();

    // ---- epilogue: boxes/scores/labels/valid (fp32) ----
    if (t < MAXDET) {
        int kept = s_kept;
        float4 obx = make_float4(0.f, 0.f, 0.f, 0.f);
        float osc = 0.f, olab = -1.f, oval = 0.f;
        if (t < kept) {
            int idx = s_kidx[t];
            obx  = boxes[idx];              // raw (non-offset) box
            osc  = s_kscr[t];
            olab = (float)s_klab[t];
            oval = 1.f;
        }
        float* ob = out + ((size_t)b * MAXDET + t) * 4;
        ob[0] = obx.x; ob[1] = obx.y; ob[2] = obx.z; ob[3] = obx.w;
        out[BATCH * MAXDET * 4 + b * MAXDET + t] = osc;
        out[BATCH * MAXDET * 5 + b * MAXDET + t] = olab;
        out[BATCH * MAXDET * 6 + b * MAXDET + t] = oval;
    }
}

extern "C" void kernel_launch(void* const* d_in, const int* in_sizes, int n_in,
                              void* d_out, int out_size, void* d_ws, size_t ws_size,
                              hipStream_t stream) {
    // setup_inputs() dict order: cls0, reg0, obj0, cls1, reg1, obj1, cls2, reg2, obj2
    const float* cls0 = (const float*)d_in[0];
    const float* reg0 = (const float*)d_in[1];
    const float* obj0 = (const float*)d_in[2];
    const float* cls1 = (const float*)d_in[3];
    const float* reg1 = (const float*)d_in[4];
    const float* obj1 = (const float*)d_in[5];
    const float* cls2 = (const float*)d_in[6];
    const float* reg2 = (const float*)d_in[7];
    const float* obj2 = (const float*)d_in[8];

    // ws layout: boxes | labels | keys
    char* ws = (char*)d_ws;
    size_t nBA = (size_t)BATCH * NA;
    float4* wboxes  = (float4*)ws;
    int*    wlabels = (int*)(ws + nBA * 16);
    uint*   wkeys   = (uint*)(ws + nBA * 20);

    decode_kernel<<<BATCH * DGROUPS, 256, 0, stream>>>(
        cls0, reg0, obj0, cls1, reg1, obj1, cls2, reg2, obj2,
        wboxes, wlabels, wkeys);

    nms_kernel<<<BATCH, NT, 0, stream>>>(wboxes, wlabels, wkeys, (float*)d_out);
}

// Round 14
// 158.828 us; speedup vs baseline: 1.0342x; 1.0122x over previous
//
#include <hip/hip_runtime.h>
#include <cmath>

typedef unsigned int uint;
typedef unsigned long long ull;

#define BATCH 32
#define NA 8400
#define NC 80
#define MAXDET 100
#define NMSTHR 0.65f
#define SCTHR 0.01f

#define NT 1024         // NMS threads per block (16 waves -- r12 proved 8 is worse)
#define NW (NT / 64)
#define EPT 9           // ceil(NA / NT)
#define NBINS 4096      // histogram bins on key[31:20]
#define CAP 512         // candidate buffer (giant-bin overflow safety)
#define WTGT 256u       // window target size

#define DGROUPS 132     // 64-anchor groups per image: 100 (L0) + 25 (L1) + 7 (L2)

__device__ __forceinline__ float stable_sigmoid(float x) {
    if (x >= 0.f) return 1.f / (1.f + expf(-x));
    float e = expf(x);
    return e / (1.f + e);
}

// ---------------- decode: one 256-thread block per 64 anchors ----------------
// r7 structure + ONE addition: wave 0's epilogue (which already holds each
// box's coords in registers) wave-reduces max|coord| and stores ONE float to
// gmax[block] -- so nms no longer re-reads 134 KB/image of boxes for amax.
// The reduce lives entirely inside the wave-uniform w==0 branch, consumes
// only locally-live values, no atomics, no function-tail live range (r4's
// regalloc-collapse mode). Invalid tail lanes use HW-1-clamped coords:
// duplicates are harmless under max.
template<int HW, int W, int S>
__device__ __forceinline__ void decode_blk(
    const float* __restrict__ cls, const float* __restrict__ reg,
    const float* __restrict__ obj, int b, int p0, int w, int lane, int ag0,
    float (*s_m)[64], int (*s_c)[64],
    float4* __restrict__ wboxes, int* __restrict__ wlabels, uint* __restrict__ wkeys,
    float* __restrict__ gslot)
{
    int p = p0 + lane;
    bool valid = (p < HW);            // only the last L2 group has invalid lanes
    int pc = valid ? p : (HW - 1);    // clamped for safe (dup) loads

    const float* cbase = cls + (size_t)b * NC * HW + (size_t)(w * 20) * HW + pc;
    float v[20];
    #pragma unroll
    for (int i = 0; i < 20; ++i) v[i] = cbase[(size_t)i * HW];
    float m = v[0]; int c = 0;
    #pragma unroll
    for (int i = 1; i < 20; ++i)
        if (v[i] > m) { m = v[i]; c = i; }     // strict > -> first max in slice

    s_m[w][lane] = m;
    s_c[w][lane] = c + w * 20;
    __syncthreads();

    if (w == 0) {
        float mm = s_m[0][lane]; int cc = s_c[0][lane];
        #pragma unroll
        for (int ww = 1; ww < 4; ++ww) {
            float om = s_m[ww][lane]; int oc = s_c[ww][lane];
            if (om > mm) { mm = om; cc = oc; } // strict > keeps lowest channel
        }
        const float* rb = reg + (size_t)b * 4 * HW + pc;
        float r0 = rb[0];
        float r1 = rb[HW];
        float r2 = rb[2 * (size_t)HW];
        float r3 = rb[3 * (size_t)HW];
        float ov = obj[(size_t)b * HW + pc];

        int y = pc / W;               // W constexpr -> magic mul
        int x = pc - y * W;
        float sc = stable_sigmoid(mm) * stable_sigmoid(ov);
        float cx = r0 * (float)S + (float)x * (float)S;
        float cy = r1 * (float)S + (float)y * (float)S;
        float bw = expf(r2) * (float)S;
        float bh = expf(r3) * (float)S;
        float x1 = cx - bw * 0.5f, y1 = cy - bh * 0.5f;
        float x2 = cx + bw * 0.5f, y2 = cy + bh * 0.5f;

        if (valid) {
            int ag = ag0 + lane;
            wboxes[ag]  = make_float4(x1, y1, x2, y2);
            wlabels[ag] = cc;
            wkeys[ag]   = (sc >= SCTHR) ? ~__float_as_uint(sc) : 0xFFFFFFFFu;
        }

        // per-block max|coord| (dup-clamped coords fine under max)
        float am = fmaxf(fmaxf(fabsf(x1), fabsf(y1)), fmaxf(fabsf(x2), fabsf(y2)));
        #pragma unroll
        for (int o = 1; o < 64; o <<= 1) am = fmaxf(am, __shfl_xor(am, o));
        if (lane == 0) *gslot = am;
    }
}

__global__ __launch_bounds__(256) void decode_kernel(
    const float* __restrict__ cls0, const float* __restrict__ reg0, const float* __restrict__ obj0,
    const float* __restrict__ cls1, const float* __restrict__ reg1, const float* __restrict__ obj1,
    const float* __restrict__ cls2, const float* __restrict__ reg2, const float* __restrict__ obj2,
    float4* __restrict__ wboxes, int* __restrict__ wlabels, uint* __restrict__ wkeys,
    float* __restrict__ gmax)
{
    __shared__ float s_m[4][64];
    __shared__ int   s_c[4][64];

    int bid  = blockIdx.x;            // BATCH * DGROUPS blocks
    int b    = bid / DGROUPS;         // literal divisor -> magic mul
    int g    = bid - b * DGROUPS;
    int t    = threadIdx.x;
    int w    = t >> 6;
    int lane = t & 63;
    float* gslot = gmax + bid;        // one slot per block, written by wave 0

    if (g < 100) {
        int p0 = g * 64;
        decode_blk<6400, 80, 8>(cls0, reg0, obj0, b, p0, w, lane,
                                b * NA + p0, s_m, s_c, wboxes, wlabels, wkeys, gslot);
    } else if (g < 125) {
        int p0 = (g - 100) * 64;
        decode_blk<1600, 40, 16>(cls1, reg1, obj1, b, p0, w, lane,
                                 b * NA + 6400 + p0, s_m, s_c, wboxes, wlabels, wkeys, gslot);
    } else {
        int p0 = (g - 125) * 64;
        decode_blk<400, 20, 32>(cls2, reg2, obj2, b, p0, w, lane,
                                b * NA + 8000 + p0, s_m, s_c, wboxes, wlabels, wkeys, gslot);
    }
}

// ---------------- NMS via sorted walk (r13 + keys-only sweep) ---------------
// vs r13 (41.2 us): the front sweep no longer reads boxes (its only consumer
// was amax, now precomputed per-block by decode into gmax). amax = max over
// the image's 132 gmax floats, fed through the existing reduction tree.
// Sweep reads keys only (4 B/anchor instead of 20 B). Everything else
// byte-identical to r13.
__global__ __launch_bounds__(NT) void nms_kernel(
    const float4* __restrict__ wboxes, const int* __restrict__ wlabels,
    const uint* __restrict__ wkeys, const float* __restrict__ gmax,
    float* __restrict__ out)
{
    int b = blockIdx.x;
    int t = threadIdx.x;
    int lane = t & 63;
    int wv = t >> 6;
    const float4* boxes  = wboxes  + (size_t)b * NA;
    const int*    labels = wlabels + (size_t)b * NA;
    const uint*   keys   = wkeys   + (size_t)b * NA;

    __shared__ uint   s_hist[NBINS];
    __shared__ uint   s_cum[NBINS + 1];    // exclusive prefix
    __shared__ uint   s_wsum[NW];
    __shared__ ull    s_skey[CAP];
    __shared__ float4 s_cbox[CAP];         // candidate OFFSET boxes (prefetched)
    __shared__ float  s_ca[CAP];           // candidate offset-box areas
    __shared__ int    s_clb[CAP];          // candidate labels
    __shared__ float  s_kbox[MAXDET][4];   // kept OFFSET boxes
    __shared__ float  s_ka1[MAXDET];
    __shared__ int    s_kidx[MAXDET];
    __shared__ float  s_kscr[MAXDET];
    __shared__ int    s_klab[MAXDET];
    __shared__ float  s_red[NW];
    __shared__ float  s_off;
    __shared__ int    s_kept, s_winlo, s_winhi, s_nsel;

    // ---- zero hist; amax from gmax; keys-only sweep: histogram + key cache ----
    for (int i = t; i < NBINS; i += NT) s_hist[i] = 0;
    if (t == 0) { s_kept = 0; s_winlo = 0; }
    __syncthreads();
    float m = (t < DGROUPS) ? gmax[b * DGROUPS + t] : 0.f;
    uint kreg[EPT];                        // per-thread key cache (const-indexed)
    #pragma unroll
    for (int w = 0; w < EPT; ++w) {
        int e = t + w * NT;
        kreg[w] = 0xFFFFFFFFu;
        if (e < NA) {
            uint k = keys[e];
            kreg[w] = k;
            if (k != 0xFFFFFFFFu) atomicAdd(&s_hist[k >> 20], 1u);
        }
    }
    #pragma unroll
    for (int o = 32; o >= 1; o >>= 1) m = fmaxf(m, __shfl_xor(m, o));
    if (lane == 0) s_red[wv] = m;
    __syncthreads();
    if (t == 0) {
        float mm = 0.f;
        for (int w = 0; w < NW; ++w) mm = fmaxf(mm, s_red[w]);
        s_off = mm + 1.f;
    }

    // ---- exclusive scan over 4096 bins: 4 bins/thread + shfl scans ----
    uint l0 = s_hist[4 * t], l1 = s_hist[4 * t + 1],
         l2 = s_hist[4 * t + 2], l3 = s_hist[4 * t + 3];
    uint L = l0 + l1 + l2 + l3;
    uint ls = L;
    #pragma unroll
    for (int o = 1; o < 64; o <<= 1) {
        uint v = __shfl_up(ls, o);
        if (lane >= o) ls += v;
    }
    if (lane == 63) s_wsum[wv] = ls;
    __syncthreads();
    if (t < NW) {
        uint v = s_wsum[t];
        uint vs = v;
        #pragma unroll
        for (int o = 1; o < NW; o <<= 1) {
            uint u = __shfl_up(vs, o);
            if ((t & 63) >= o) vs += u;
        }
        s_wsum[t] = vs - v;
    }
    __syncthreads();
    uint base = s_wsum[wv] + (ls - L);
    s_cum[4 * t]     = base;
    s_cum[4 * t + 1] = base + l0;
    s_cum[4 * t + 2] = base + l0 + l1;
    s_cum[4 * t + 3] = base + l0 + l1 + l2;
    if (t == NT - 1) s_cum[NBINS] = base + L;
    float off;

    // ---- window loop (typically runs once) ----
    for (;;) {
        __syncthreads();
        int kept = s_kept, winlo = s_winlo;
        uint remaining = s_cum[NBINS] - s_cum[winlo];
        if (kept >= MAXDET || winlo >= NBINS || remaining == 0u) break;
        if (t == 0) { s_winhi = winlo + 1; s_nsel = 0; }   // giant-bin clamp floor
        if (t < CAP) s_skey[t] = ~0ull;
        __syncthreads();
        // winhi via unique-boundary store: pred(i) = cum[i+1]-cl <= WTGT is
        // monotone non-increasing in i, so exactly one i has pred(i) && !pred(i+1).
        uint cl = s_cum[winlo];
        #pragma unroll
        for (int q = 0; q < 4; ++q) {
            int i = t + q * NT;
            if (i >= winlo && i < NBINS) {
                bool p0 = (s_cum[i + 1] - cl) <= WTGT;
                bool p1 = (i + 1 < NBINS) && ((s_cum[i + 2] - cl) <= WTGT);
                if (p0 && !p1) s_winhi = i + 1;   // unique writer
            }
        }
        __syncthreads();
        int winhi = s_winhi;

        // wave-aggregated compaction of window candidates (keys from REGISTERS)
        #pragma unroll
        for (int w = 0; w < EPT; ++w) {
            int e = t + w * NT;
            uint k = kreg[w];
            bool q = false;
            if (k != 0xFFFFFFFFu) {
                int bin = (int)(k >> 20);
                q = (bin >= winlo && bin < winhi);
            }
            ull mask = __ballot(q);
            if (mask) {
                int leader = __ffsll(mask) - 1;
                int pbase = 0;
                if (lane == leader) pbase = atomicAdd(&s_nsel, __popcll(mask));
                pbase = __shfl(pbase, leader);
                if (q) {
                    int pos = pbase + __popcll(mask & ((1ull << lane) - 1ull));
                    if (pos < CAP) s_skey[pos] = ((ull)k << 32) | (uint)e;
                }
            }
        }
        __syncthreads();
        int nsel = s_nsel; if (nsel > CAP) nsel = CAP;

        // O(n) rank-placement sort: position = count of smaller keys (keys
        // totally ordered via embedded anchor idx). Uniform LDS broadcast
        // loop; then scatter s_skey[rank] AND prefetch the candidate's
        // box/label into s_cbox[rank]/s_ca/s_clb in the SAME phase.
        off = s_off;
        ull myk = (t < nsel) ? s_skey[t] : ~0ull;
        int rank = 0;
        if (t < nsel) {
            for (int j = 0; j < nsel; ++j)
                rank += (s_skey[j] < myk) ? 1 : 0;
        }
        __syncthreads();
        if (t < nsel) {
            s_skey[rank] = myk;
            int idx = (int)(myk & 0xFFFFFFFFull);
            float4 rb = boxes[idx];
            int lb = labels[idx];
            float lo = (float)lb * off;
            float c0 = rb.x + lo, c1 = rb.y + lo;
            float c2 = rb.z + lo, c3 = rb.w + lo;
            s_cbox[rank] = make_float4(c0, c1, c2, c3);
            s_ca[rank]   = (c2 - c0) * (c3 - c1);
            s_clb[rank]  = lb;
        }
        __syncthreads();

        // sorted walk on wave 0 (per-accept IoU; 5 shfls + lane-f writes)
        if (t < 64) {
            int kept2 = s_kept;
            for (int cb = 0; cb < nsel && kept2 < MAXDET; cb += 64) {
                int ci = cb + lane;
                ull sk = (ci < nsel) ? s_skey[ci] : ~0ull;
                bool has = (sk != ~0ull);
                int idx = 0, lab = 0;
                float sc = 0.f, c0 = 0.f, c1 = 0.f, c2 = 0.f, c3 = 0.f, ca = 0.f;
                if (has) {
                    idx = (int)(sk & 0xFFFFFFFFull);
                    sc  = __uint_as_float(~(uint)(sk >> 32));   // exact score bits
                    float4 cbx = s_cbox[ci];
                    c0 = cbx.x; c1 = cbx.y; c2 = cbx.z; c3 = cbx.w;
                    ca = s_ca[ci];
                    lab = s_clb[ci];
                    for (int q = 0; q < kept2; ++q) {
                        float tlx = fmaxf(s_kbox[q][0], c0);
                        float tly = fmaxf(s_kbox[q][1], c1);
                        float brx = fminf(s_kbox[q][2], c2);
                        float bry = fminf(s_kbox[q][3], c3);
                        float ww = fmaxf(brx - tlx, 0.f);
                        float hh = fmaxf(bry - tly, 0.f);
                        float inter = ww * hh;
                        float iou = inter / (s_ka1[q] + ca - inter + 1e-6f);
                        if (iou > NMSTHR) { has = false; break; }
                    }
                }
                ull am = __ballot(has);
                while (am && kept2 < MAXDET) {
                    int f = __ffsll(am) - 1;
                    float f0 = __shfl(c0, f), f1 = __shfl(c1, f);
                    float f2 = __shfl(c2, f), f3 = __shfl(c3, f);
                    float fa = __shfl(ca, f);
                    if (lane == f) {
                        s_kbox[kept2][0] = c0; s_kbox[kept2][1] = c1;
                        s_kbox[kept2][2] = c2; s_kbox[kept2][3] = c3;
                        s_ka1[kept2] = ca; s_kidx[kept2] = idx;
                        s_kscr[kept2] = sc; s_klab[kept2] = lab;
                        has = false;
                    }
                    kept2++;
                    if (has) {
                        float tlx = fmaxf(f0, c0), tly = fmaxf(f1, c1);
                        float brx = fminf(f2, c2), bry = fminf(f3, c3);
                        float ww = fmaxf(brx - tlx, 0.f), hh = fmaxf(bry - tly, 0.f);
                        float inter = ww * hh;
                        float iou = inter / (fa + ca - inter + 1e-6f);
                        if (iou > NMSTHR) has = false;
                    }
                    am = __ballot(has);
                }
            }
            if (lane == 0) s_kept = kept2;
        }
        __syncthreads();
        if (t == 0) s_winlo = s_winhi;
    }
    __syncthreads();

    // ---- epilogue: boxes/scores/labels/valid (fp32) ----
    if (t < MAXDET) {
        int kept = s_kept;
        float4 obx = make_float4(0.f, 0.f, 0.f, 0.f);
        float osc = 0.f, olab = -1.f, oval = 0.f;
        if (t < kept) {
            int idx = s_kidx[t];
            obx  = boxes[idx];              // raw (non-offset) box
            osc  = s_kscr[t];
            olab = (float)s_klab[t];
            oval = 1.f;
        }
        float* ob = out + ((size_t)b * MAXDET + t) * 4;
        ob[0] = obx.x; ob[1] = obx.y; ob[2] = obx.z; ob[3] = obx.w;
        out[BATCH * MAXDET * 4 + b * MAXDET + t] = osc;
        out[BATCH * MAXDET * 5 + b * MAXDET + t] = olab;
        out[BATCH * MAXDET * 6 + b * MAXDET + t] = oval;
    }
}

extern "C" void kernel_launch(void* const* d_in, const int* in_sizes, int n_in,
                              void* d_out, int out_size, void* d_ws, size_t ws_size,
                              hipStream_t stream) {
    // setup_inputs() dict order: cls0, reg0, obj0, cls1, reg1, obj1, cls2, reg2, obj2
    const float* cls0 = (const float*)d_in[0];
    const float* reg0 = (const float*)d_in[1];
    const float* obj0 = (const float*)d_in[2];
    const float* cls1 = (const float*)d_in[3];
    const float* reg1 = (const float*)d_in[4];
    const float* obj1 = (const float*)d_in[5];
    const float* cls2 = (const float*)d_in[6];
    const float* reg2 = (const float*)d_in[7];
    const float* obj2 = (const float*)d_in[8];

    // ws layout: boxes | labels | keys | gmax
    char* ws = (char*)d_ws;
    size_t nBA = (size_t)BATCH * NA;
    float4* wboxes  = (float4*)ws;
    int*    wlabels = (int*)(ws + nBA * 16);
    uint*   wkeys   = (uint*)(ws + nBA * 20);
    float*  wgmax   = (float*)(ws + nBA * 24);   // BATCH*DGROUPS floats

    decode_kernel<<<BATCH * DGROUPS, 256, 0, stream>>>(
        cls0, reg0, obj0, cls1, reg1, obj1, cls2, reg2, obj2,
        wboxes, wlabels, wkeys, wgmax);

    nms_kernel<<<BATCH, NT, 0, stream>>>(wboxes, wlabels, wkeys, wgmax,
                                         (float*)d_out);
}

// Round 15
// 158.631 us; speedup vs baseline: 1.0355x; 1.0012x over previous
//
#include <hip/hip_runtime.h>
#include <cmath>

typedef unsigned int uint;
typedef unsigned long long ull;

#define BATCH 32
#define NA 8400
#define NC 80
#define MAXDET 100
#define NMSTHR 0.65f
#define SCTHR 0.01f

#define NT 1024         // NMS threads per block (16 waves -- r12 proved 8 is worse)
#define NW (NT / 64)
#define EPT 9           // ceil(NA / NT)
#define NBINS 4096      // histogram bins on key[31:20]
#define CAP 512         // candidate buffer (giant-bin overflow safety)
#define WTGT 256u       // window target size

#define DGROUPS 67      // 128-anchor groups per image: 50 (L0) + 13 (L1) + 4 (L2)
#define GSLOTS (DGROUPS * 2)   // two amax slots per group (one per epilogue wave)

__device__ __forceinline__ float stable_sigmoid(float x) {
    if (x >= 0.f) return 1.f / (1.f + expf(-x));
    float e = expf(x);
    return e / (1.f + e);
}

// ---------------- decode: one 256-thread block per 128 anchors --------------
// vs r14 (ONE change): each lane loads a float2 (2 consecutive anchors), so a
// wave covers 128 anchors per channel and every cls load is ONE contiguous
// 512B segment -- half the VMEM instructions of r7/r14's 256B shape at the
// same MLP (20 outstanding loads/wave, v[20] float2 = 40 VGPRs). 2144 blocks
// = 8576 waves (~33/CU) keep the memory system fed. Epilogue on waves 0-1
// (128 anchors, unit-stride); per-wave amax -> 2 gmax slots per block.
// Tail groups clamp the load base (HW even -> float2-safe) and skip stores.
template<int HW, int W, int S>
__device__ __forceinline__ void decode_blk(
    const float* __restrict__ cls, const float* __restrict__ reg,
    const float* __restrict__ obj, int b, int p0, int w, int lane, int ag0,
    float (*s_m)[128], int (*s_c)[128],
    float4* __restrict__ wboxes, int* __restrict__ wlabels, uint* __restrict__ wkeys,
    float* __restrict__ gbase)
{
    int a2  = p0 + 2 * lane;                    // first anchor of this lane's pair
    int pc2 = (a2 + 1 < HW) ? a2 : (HW - 2);    // clamp: both elems in-bounds

    const float* cbase = cls + (size_t)b * NC * HW + (size_t)(w * 20) * HW + pc2;
    float2 v[20];
    #pragma unroll
    for (int i = 0; i < 20; ++i) v[i] = *(const float2*)(cbase + (size_t)i * HW);
    float m0 = v[0].x, m1 = v[0].y;
    int   c0 = 0,      c1 = 0;
    #pragma unroll
    for (int i = 1; i < 20; ++i) {
        if (v[i].x > m0) { m0 = v[i].x; c0 = i; }   // strict > -> first max
        if (v[i].y > m1) { m1 = v[i].y; c1 = i; }
    }
    s_m[w][2 * lane]     = m0;
    s_c[w][2 * lane]     = c0 + w * 20;
    s_m[w][2 * lane + 1] = m1;
    s_c[w][2 * lane + 1] = c1 + w * 20;
    __syncthreads();

    if (w < 2) {                                // epilogue: waves 0-1, anchor p0+tt
        int tt = w * 64 + lane;
        int p  = p0 + tt;
        bool valid = (p < HW);
        int pc = valid ? p : (HW - 1);

        float mm = s_m[0][tt]; int cc = s_c[0][tt];
        #pragma unroll
        for (int ww = 1; ww < 4; ++ww) {
            float om = s_m[ww][tt]; int oc = s_c[ww][tt];
            if (om > mm) { mm = om; cc = oc; }  // strict > keeps lowest channel
        }
        const float* rb = reg + (size_t)b * 4 * HW + pc;
        float r0 = rb[0];
        float r1 = rb[HW];
        float r2 = rb[2 * (size_t)HW];
        float r3 = rb[3 * (size_t)HW];
        float ov = obj[(size_t)b * HW + pc];

        int y = pc / W;               // W constexpr -> magic mul
        int x = pc - y * W;
        float sc = stable_sigmoid(mm) * stable_sigmoid(ov);
        float cx = r0 * (float)S + (float)x * (float)S;
        float cy = r1 * (float)S + (float)y * (float)S;
        float bw = expf(r2) * (float)S;
        float bh = expf(r3) * (float)S;
        float x1 = cx - bw * 0.5f, y1 = cy - bh * 0.5f;
        float x2 = cx + bw * 0.5f, y2 = cy + bh * 0.5f;

        if (valid) {
            int ag = ag0 + tt;
            wboxes[ag]  = make_float4(x1, y1, x2, y2);
            wlabels[ag] = cc;
            wkeys[ag]   = (sc >= SCTHR) ? ~__float_as_uint(sc) : 0xFFFFFFFFu;
        }

        // per-wave max|coord| (dup-clamped coords fine under max)
        float am = fmaxf(fmaxf(fabsf(x1), fabsf(y1)), fmaxf(fabsf(x2), fabsf(y2)));
        #pragma unroll
        for (int o = 1; o < 64; o <<= 1) am = fmaxf(am, __shfl_xor(am, o));
        if (lane == 0) gbase[w] = am;
    }
}

__global__ __launch_bounds__(256) void decode_kernel(
    const float* __restrict__ cls0, const float* __restrict__ reg0, const float* __restrict__ obj0,
    const float* __restrict__ cls1, const float* __restrict__ reg1, const float* __restrict__ obj1,
    const float* __restrict__ cls2, const float* __restrict__ reg2, const float* __restrict__ obj2,
    float4* __restrict__ wboxes, int* __restrict__ wlabels, uint* __restrict__ wkeys,
    float* __restrict__ gmax)
{
    __shared__ float s_m[4][128];
    __shared__ int   s_c[4][128];

    int bid  = blockIdx.x;            // BATCH * DGROUPS blocks
    int b    = bid / DGROUPS;         // literal divisor -> magic mul
    int g    = bid - b * DGROUPS;
    int t    = threadIdx.x;
    int w    = t >> 6;
    int lane = t & 63;
    float* gbase = gmax + (size_t)bid * 2;   // 2 slots per block (waves 0,1)

    if (g < 50) {
        int p0 = g * 128;
        decode_blk<6400, 80, 8>(cls0, reg0, obj0, b, p0, w, lane,
                                b * NA + p0, s_m, s_c, wboxes, wlabels, wkeys, gbase);
    } else if (g < 63) {
        int p0 = (g - 50) * 128;
        decode_blk<1600, 40, 16>(cls1, reg1, obj1, b, p0, w, lane,
                                 b * NA + 6400 + p0, s_m, s_c, wboxes, wlabels, wkeys, gbase);
    } else {
        int p0 = (g - 63) * 128;
        decode_blk<400, 20, 32>(cls2, reg2, obj2, b, p0, w, lane,
                                b * NA + 8000 + p0, s_m, s_c, wboxes, wlabels, wkeys, gbase);
    }
}

// ---------------- NMS via sorted walk (r14-EXACT except GSLOTS amax read) ---
__global__ __launch_bounds__(NT) void nms_kernel(
    const float4* __restrict__ wboxes, const int* __restrict__ wlabels,
    const uint* __restrict__ wkeys, const float* __restrict__ gmax,
    float* __restrict__ out)
{
    int b = blockIdx.x;
    int t = threadIdx.x;
    int lane = t & 63;
    int wv = t >> 6;
    const float4* boxes  = wboxes  + (size_t)b * NA;
    const int*    labels = wlabels + (size_t)b * NA;
    const uint*   keys   = wkeys   + (size_t)b * NA;

    __shared__ uint   s_hist[NBINS];
    __shared__ uint   s_cum[NBINS + 1];    // exclusive prefix
    __shared__ uint   s_wsum[NW];
    __shared__ ull    s_skey[CAP];
    __shared__ float4 s_cbox[CAP];         // candidate OFFSET boxes (prefetched)
    __shared__ float  s_ca[CAP];           // candidate offset-box areas
    __shared__ int    s_clb[CAP];          // candidate labels
    __shared__ float  s_kbox[MAXDET][4];   // kept OFFSET boxes
    __shared__ float  s_ka1[MAXDET];
    __shared__ int    s_kidx[MAXDET];
    __shared__ float  s_kscr[MAXDET];
    __shared__ int    s_klab[MAXDET];
    __shared__ float  s_red[NW];
    __shared__ float  s_off;
    __shared__ int    s_kept, s_winlo, s_winhi, s_nsel;

    // ---- zero hist; amax from gmax; keys-only sweep: histogram + key cache ----
    for (int i = t; i < NBINS; i += NT) s_hist[i] = 0;
    if (t == 0) { s_kept = 0; s_winlo = 0; }
    __syncthreads();
    float m = (t < GSLOTS) ? gmax[b * GSLOTS + t] : 0.f;
    uint kreg[EPT];                        // per-thread key cache (const-indexed)
    #pragma unroll
    for (int w = 0; w < EPT; ++w) {
        int e = t + w * NT;
        kreg[w] = 0xFFFFFFFFu;
        if (e < NA) {
            uint k = keys[e];
            kreg[w] = k;
            if (k != 0xFFFFFFFFu) atomicAdd(&s_hist[k >> 20], 1u);
        }
    }
    #pragma unroll
    for (int o = 32; o >= 1; o >>= 1) m = fmaxf(m, __shfl_xor(m, o));
    if (lane == 0) s_red[wv] = m;
    __syncthreads();
    if (t == 0) {
        float mm = 0.f;
        for (int w = 0; w < NW; ++w) mm = fmaxf(mm, s_red[w]);
        s_off = mm + 1.f;
    }

    // ---- exclusive scan over 4096 bins: 4 bins/thread + shfl scans ----
    uint l0 = s_hist[4 * t], l1 = s_hist[4 * t + 1],
         l2 = s_hist[4 * t + 2], l3 = s_hist[4 * t + 3];
    uint L = l0 + l1 + l2 + l3;
    uint ls = L;
    #pragma unroll
    for (int o = 1; o < 64; o <<= 1) {
        uint v = __shfl_up(ls, o);
        if (lane >= o) ls += v;
    }
    if (lane == 63) s_wsum[wv] = ls;
    __syncthreads();
    if (t < NW) {
        uint v = s_wsum[t];
        uint vs = v;
        #pragma unroll
        for (int o = 1; o < NW; o <<= 1) {
            uint u = __shfl_up(vs, o);
            if ((t & 63) >= o) vs += u;
        }
        s_wsum[t] = vs - v;
    }
    __syncthreads();
    uint base = s_wsum[wv] + (ls - L);
    s_cum[4 * t]     = base;
    s_cum[4 * t + 1] = base + l0;
    s_cum[4 * t + 2] = base + l0 + l1;
    s_cum[4 * t + 3] = base + l0 + l1 + l2;
    if (t == NT - 1) s_cum[NBINS] = base + L;
    float off;

    // ---- window loop (typically runs once) ----
    for (;;) {
        __syncthreads();
        int kept = s_kept, winlo = s_winlo;
        uint remaining = s_cum[NBINS] - s_cum[winlo];
        if (kept >= MAXDET || winlo >= NBINS || remaining == 0u) break;
        if (t == 0) { s_winhi = winlo + 1; s_nsel = 0; }   // giant-bin clamp floor
        if (t < CAP) s_skey[t] = ~0ull;
        __syncthreads();
        // winhi via unique-boundary store: pred(i) = cum[i+1]-cl <= WTGT is
        // monotone non-increasing in i, so exactly one i has pred(i) && !pred(i+1).
        uint cl = s_cum[winlo];
        #pragma unroll
        for (int q = 0; q < 4; ++q) {
            int i = t + q * NT;
            if (i >= winlo && i < NBINS) {
                bool p0 = (s_cum[i + 1] - cl) <= WTGT;
                bool p1 = (i + 1 < NBINS) && ((s_cum[i + 2] - cl) <= WTGT);
                if (p0 && !p1) s_winhi = i + 1;   // unique writer
            }
        }
        __syncthreads();
        int winhi = s_winhi;

        // wave-aggregated compaction of window candidates (keys from REGISTERS)
        #pragma unroll
        for (int w = 0; w < EPT; ++w) {
            int e = t + w * NT;
            uint k = kreg[w];
            bool q = false;
            if (k != 0xFFFFFFFFu) {
                int bin = (int)(k >> 20);
                q = (bin >= winlo && bin < winhi);
            }
            ull mask = __ballot(q);
            if (mask) {
                int leader = __ffsll(mask) - 1;
                int pbase = 0;
                if (lane == leader) pbase = atomicAdd(&s_nsel, __popcll(mask));
                pbase = __shfl(pbase, leader);
                if (q) {
                    int pos = pbase + __popcll(mask & ((1ull << lane) - 1ull));
                    if (pos < CAP) s_skey[pos] = ((ull)k << 32) | (uint)e;
                }
            }
        }
        __syncthreads();
        int nsel = s_nsel; if (nsel > CAP) nsel = CAP;

        // O(n) rank-placement sort: position = count of smaller keys (keys
        // totally ordered via embedded anchor idx). Uniform LDS broadcast
        // loop; then scatter s_skey[rank] AND prefetch the candidate's
        // box/label into s_cbox[rank]/s_ca/s_clb in the SAME phase.
        off = s_off;
        ull myk = (t < nsel) ? s_skey[t] : ~0ull;
        int rank = 0;
        if (t < nsel) {
            for (int j = 0; j < nsel; ++j)
                rank += (s_skey[j] < myk) ? 1 : 0;
        }
        __syncthreads();
        if (t < nsel) {
            s_skey[rank] = myk;
            int idx = (int)(myk & 0xFFFFFFFFull);
            float4 rb = boxes[idx];
            int lb = labels[idx];
            float lo = (float)lb * off;
            float c0 = rb.x + lo, c1 = rb.y + lo;
            float c2 = rb.z + lo, c3 = rb.w + lo;
            s_cbox[rank] = make_float4(c0, c1, c2, c3);
            s_ca[rank]   = (c2 - c0) * (c3 - c1);
            s_clb[rank]  = lb;
        }
        __syncthreads();

        // sorted walk on wave 0 (per-accept IoU; 5 shfls + lane-f writes)
        if (t < 64) {
            int kept2 = s_kept;
            for (int cb = 0; cb < nsel && kept2 < MAXDET; cb += 64) {
                int ci = cb + lane;
                ull sk = (ci < nsel) ? s_skey[ci] : ~0ull;
                bool has = (sk != ~0ull);
                int idx = 0, lab = 0;
                float sc = 0.f, c0 = 0.f, c1 = 0.f, c2 = 0.f, c3 = 0.f, ca = 0.f;
                if (has) {
                    idx = (int)(sk & 0xFFFFFFFFull);
                    sc  = __uint_as_float(~(uint)(sk >> 32));   // exact score bits
                    float4 cbx = s_cbox[ci];
                    c0 = cbx.x; c1 = cbx.y; c2 = cbx.z; c3 = cbx.w;
                    ca = s_ca[ci];
                    lab = s_clb[ci];
                    for (int q = 0; q < kept2; ++q) {
                        float tlx = fmaxf(s_kbox[q][0], c0);
                        float tly = fmaxf(s_kbox[q][1], c1);
                        float brx = fminf(s_kbox[q][2], c2);
                        float bry = fminf(s_kbox[q][3], c3);
                        float ww = fmaxf(brx - tlx, 0.f);
                        float hh = fmaxf(bry - tly, 0.f);
                        float inter = ww * hh;
                        float iou = inter / (s_ka1[q] + ca - inter + 1e-6f);
                        if (iou > NMSTHR) { has = false; break; }
                    }
                }
                ull am = __ballot(has);
                while (am && kept2 < MAXDET) {
                    int f = __ffsll(am) - 1;
                    float f0 = __shfl(c0, f), f1 = __shfl(c1, f);
                    float f2 = __shfl(c2, f), f3 = __shfl(c3, f);
                    float fa = __shfl(ca, f);
                    if (lane == f) {
                        s_kbox[kept2][0] = c0; s_kbox[kept2][1] = c1;
                        s_kbox[kept2][2] = c2; s_kbox[kept2][3] = c3;
                        s_ka1[kept2] = ca; s_kidx[kept2] = idx;
                        s_kscr[kept2] = sc; s_klab[kept2] = lab;
                        has = false;
                    }
                    kept2++;
                    if (has) {
                        float tlx = fmaxf(f0, c0), tly = fmaxf(f1, c1);
                        float brx = fminf(f2, c2), bry = fminf(f3, c3);
                        float ww = fmaxf(brx - tlx, 0.f), hh = fmaxf(bry - tly, 0.f);
                        float inter = ww * hh;
                        float iou = inter / (fa + ca - inter + 1e-6f);
                        if (iou > NMSTHR) has = false;
                    }
                    am = __ballot(has);
                }
            }
            if (lane == 0) s_kept = kept2;
        }
        __syncthreads();
        if (t == 0) s_winlo = s_winhi;
    }
    __syncthreads();

    // ---- epilogue: boxes/scores/labels/valid (fp32) ----
    if (t < MAXDET) {
        int kept = s_kept;
        float4 obx = make_float4(0.f, 0.f, 0.f, 0.f);
        float osc = 0.f, olab = -1.f, oval = 0.f;
        if (t < kept) {
            int idx = s_kidx[t];
            obx  = boxes[idx];              // raw (non-offset) box
            osc  = s_kscr[t];
            olab = (float)s_klab[t];
            oval = 1.f;
        }
        float* ob = out + ((size_t)b * MAXDET + t) * 4;
        ob[0] = obx.x; ob[1] = obx.y; ob[2] = obx.z; ob[3] = obx.w;
        out[BATCH * MAXDET * 4 + b * MAXDET + t] = osc;
        out[BATCH * MAXDET * 5 + b * MAXDET + t] = olab;
        out[BATCH * MAXDET * 6 + b * MAXDET + t] = oval;
    }
}

extern "C" void kernel_launch(void* const* d_in, const int* in_sizes, int n_in,
                              void* d_out, int out_size, void* d_ws, size_t ws_size,
                              hipStream_t stream) {
    // setup_inputs() dict order: cls0, reg0, obj0, cls1, reg1, obj1, cls2, reg2, obj2
    const float* cls0 = (const float*)d_in[0];
    const float* reg0 = (const float*)d_in[1];
    const float* obj0 = (const float*)d_in[2];
    const float* cls1 = (const float*)d_in[3];
    const float* reg1 = (const float*)d_in[4];
    const float* obj1 = (const float*)d_in[5];
    const float* cls2 = (const float*)d_in[6];
    const float* reg2 = (const float*)d_in[7];
    const float* obj2 = (const float*)d_in[8];

    // ws layout: boxes | labels | keys | gmax
    char* ws = (char*)d_ws;
    size_t nBA = (size_t)BATCH * NA;
    float4* wboxes  = (float4*)ws;
    int*    wlabels = (int*)(ws + nBA * 16);
    uint*   wkeys   = (uint*)(ws + nBA * 20);
    float*  wgmax   = (float*)(ws + nBA * 24);   // BATCH*GSLOTS floats

    decode_kernel<<<BATCH * DGROUPS, 256, 0, stream>>>(
        cls0, reg0, obj0, cls1, reg1, obj1, cls2, reg2, obj2,
        wboxes, wlabels, wkeys, wgmax);

    nms_kernel<<<BATCH, NT, 0, stream>>>(wboxes, wlabels, wkeys, wgmax,
                                         (float*)d_out);
}